// Round 9
// baseline (706.794 us; speedup 1.0000x reference)
//
#include <hip/hip_runtime.h>
#include <math.h>

// Problem constants
constexpr int cS  = 16;
constexpr int cB  = 8;
constexpr int cNC = 5;
constexpr int cD  = 256;
constexpr int cP  = 16;
constexpr int cPD = 49;
#define LEPS 1e-5f

__device__ __forceinline__ float frcp(float x) { return __builtin_amdgcn_rcpf(x); }
__device__ __forceinline__ float sigm(float x) { return frcp(1.0f + __expf(-x)); }
__device__ __forceinline__ float gelu_t(float x) {
  const float z = 1.5957691216057308f * (x + 0.044715f * x * x * x);
  return x * frcp(1.0f + __expf(-z));
}
template<int CTRL>
__device__ __forceinline__ float dpp_mov(float v) {
  return __int_as_float(__builtin_amdgcn_update_dpp(
      0, __float_as_int(v), CTRL, 0xF, 0xF, true));
}
__device__ __forceinline__ float row_sum16(float v) {
  v += dpp_mov<0xB1>(v);
  v += dpp_mov<0x4E>(v);
  v += dpp_mov<0x124>(v);
  v += dpp_mov<0x128>(v);
  return v;
}
__device__ __forceinline__ float wave_sum64(float v) {
  v = row_sum16(v);
  v += __shfl_xor(v, 16, 64);
  v += __shfl_xor(v, 32, 64);
  return v;
}

// software grid barrier: monotonic counter, device scope. All 128 blocks are
// co-resident (1 block/CU on 256 CUs) so spinning is safe.
__device__ __forceinline__ void gbar(unsigned* cnt, unsigned target, int t) {
  __threadfence();              // release: my writes visible agent-wide
  __syncthreads();
  if (t == 0) {
    __hip_atomic_fetch_add(cnt, 1u, __ATOMIC_RELEASE, __HIP_MEMORY_SCOPE_AGENT);
    while (__hip_atomic_load(cnt, __ATOMIC_ACQUIRE, __HIP_MEMORY_SCOPE_AGENT) < target) {
      __builtin_amdgcn_s_sleep(2);
    }
  }
  __syncthreads();
  __threadfence();              // acquire: invalidate stale cache lines
}

struct Params {
  const float* x; const int* fb; const float* inW; const float* inb;
  const float *tkWy, *tkWq, *tkWk, *tkwb, *tklng, *tklnb;
  const float *tkmg, *tkmb, *tkmW1, *tkmb1, *tkmW2, *tkmb2;
  const float *chWy, *chWq, *chWk, *chwb, *chlng, *chlnb;
  const float *chmg, *chmb, *chmW1, *chmb1, *chmW2, *chmb2;
  const float *flng, *flnb;
  const float *oWy, *oWq, *oWk, *owb, *olng, *olnb, *outW, *outb;
  float* h; float* gbuf; float* outp; unsigned* cnt;
};

// LDS overlays
struct SM_M { float tile[16][256]; float W1s[1024]; float W2s[1024];
              float mean_[16]; float rstd_[16]; float red[16][17]; float red2[16][17]; };
struct SM_C { float yout[16][256]; float lnv[8][256]; float hid[8][128]; };
struct SM_F { float sacc[4][256]; };
struct SM_O { float ymat[16][256]; float gwm[cNC][256]; float GBp[4][10]; float GBs[10]; };

__global__ __launch_bounds__(256, 1) void k_fused(Params p) {
  const int bid  = blockIdx.x;
  const int t    = threadIdx.x;
  const int lane = t & 63;
  const int w    = t >> 6;
  __shared__ __align__(16) char smraw[29184];
  float* h = p.h;

  // ================= Stage E: embed (block = sb) ==========================
  {
    float* img = (float*)smraw;
    const int sb = bid;
    for (int idx = t; idx < 784; idx += 256) img[idx] = p.x[(size_t)sb * 784 + idx];
    float wreg[cPD];
#pragma unroll
    for (int j = 0; j < cPD; ++j) wreg[j] = p.inW[(size_t)j * cD + t];
    __syncthreads();
    const int cls = p.fb[sb];
    const float base0 = p.inb[t] + p.inW[(size_t)(cPD + cls) * cD + t];
#pragma unroll
    for (int pp = 0; pp < cP; ++pp) {
      const int phh = pp >> 2, pw = pp & 3;
      float acc = base0;
#pragma unroll
      for (int j = 0; j < cPD; ++j)
        acc += img[(phh * 7 + j / 7) * 28 + pw * 7 + (j % 7)] * wreg[j];
      h[((size_t)sb * cP + pp) * cD + t] = acc;
    }
  }
  gbar(p.cnt, 128u * 1, t);

  for (int i = 0; i < 2; ++i) {
    const unsigned pb = 2 + 3 * i;
    // =============== Stage T: token SRWM (block = (b, dgrp)) =============
    {
      const float* Wy0 = p.tkWy + i * 256;
      const float* Wq0 = p.tkWq + i * 256;
      const float* Wk0 = p.tkWk + i * 256;
      const float* wb0 = p.tkwb + i * 64;
      const int r  = lane & 15;
      const int li = lane >> 4;
      const int b  = bid >> 4;
      const int d  = ((bid & 15) << 4) + (w << 2) + li;
      float wy[16], wq[16], wk[16], wbr[16];
#pragma unroll
      for (int j = 0; j < 16; ++j) {
        wy[j]  = Wy0[r * 16 + j];
        wq[j]  = Wq0[r * 16 + j];
        wk[j]  = Wk0[r * 16 + j];
        wbr[j] = wb0[(r & 3) * 16 + j];
      }
      const float gg = p.tklng[i * 16 + r], bb = p.tklnb[i * 16 + r];
      float xp[16];
#pragma unroll
      for (int s = 0; s < 16; ++s)
        xp[s] = h[((size_t)(s * cB + b) * cP + r) * cD + d];
      for (int s = 0; s < cS; ++s) {
        const float xv = xp[s];
        float y = 0.f, q = 0.f, k = 0.f, bt = 0.f;
#pragma unroll
        for (int j = 0; j < 16; ++j) {
          const float xj = __shfl(xv, j, 16);
          y += wy[j] * xj; q += wq[j] * xj; k += wk[j] * xj; bt += wbr[j] * xj;
        }
        const float bsig = sigm(bt);
        const float eq = __expf(q), ek = __expf(k);
        float ay = 0.f, vyk = 0.f, vqq = 0.f, vqk = 0.f, vkq = 0.f, vkk = 0.f, vbq = 0.f, vbk = 0.f;
        float ksj[16];
#pragma unroll
        for (int j = 0; j < 16; ++j) {
          const float qj = __shfl(eq, j, 16);
          const float kj = __shfl(ek, j, 16);
          ksj[j] = kj;
          ay  += wy[j]  * qj; vyk += wy[j]  * kj;
          vqq += wq[j]  * qj; vqk += wq[j]  * kj;
          vkq += wk[j]  * qj; vkk += wk[j]  * kj;
          vbq += wbr[j] * qj; vbk += wbr[j] * kj;
        }
        const float rq = frcp(row_sum16(eq));
        const float rk = frcp(row_sum16(ek));
        const float ea = __expf(ay * rq);
        const float vyq = ea * frcp(row_sum16(ea));
        const float b0  = __shfl(bsig, 0, 16);
        const float b1v = __shfl(bsig, 1, 16);
        const float b2v = __shfl(bsig, 2, 16);
        const float b3v = __shfl(bsig, 3, 16);
        const float cy = b0  * (vyq      - vyk * rk) * rk;
        const float cq = b1v * (vqq * rq - vqk * rk) * rk;
        const float ck = b2v * (vkq * rq - vkk * rk) * rk;
        const float cb = b3v * (vbq * rq - vbk * rk) * rk;
#pragma unroll
        for (int j = 0; j < 16; ++j) {
          wy[j] += cy * ksj[j]; wq[j] += cq * ksj[j]; wk[j] += ck * ksj[j]; wbr[j] += cb * ksj[j];
        }
        const float s1 = row_sum16(y);
        const float s2 = row_sum16(y * y);
        const float m = s1 * 0.0625f;
        const float var = s2 * 0.0625f - m * m;
        h[((size_t)(s * cB + b) * cP + r) * cD + d] = (y - m) * rsqrtf(var + LEPS) * gg + bb;
      }
    }
    gbar(p.cnt, 128u * pb, t);

    // =============== Stage M: token mixer (block = sb) ===================
    {
      SM_M* sm = (SM_M*)smraw;
      const float* W1 = p.tkmW1 + i * 1024;
      const float* W2 = p.tkmW2 + i * 1024;
      const float* b1 = p.tkmb1 + i * 64;
      const float* b2 = p.tkmb2 + i * 16;
      const int sb = bid;
      const size_t base = (size_t)sb * cP * cD;
#pragma unroll
      for (int pp = 0; pp < 16; ++pp) sm->tile[pp][t] = h[base + pp * 256 + t];
      sm->W1s[t] = W1[t]; sm->W1s[t + 256] = W1[t + 256];
      sm->W1s[t + 512] = W1[t + 512]; sm->W1s[t + 768] = W1[t + 768];
      sm->W2s[t] = W2[t]; sm->W2s[t + 256] = W2[t + 256];
      sm->W2s[t + 512] = W2[t + 512]; sm->W2s[t + 768] = W2[t + 768];
      __syncthreads();
      const int pp_ = t >> 4, l = t & 15;
      float ps = 0.f, ps2 = 0.f;
#pragma unroll
      for (int k = 0; k < 16; ++k) { const float v = sm->tile[pp_][l + 16 * k]; ps += v; ps2 += v * v; }
      sm->red[pp_][l] = ps; sm->red2[pp_][l] = ps2;
      __syncthreads();
      if (t < 16) {
        float smv = 0.f, s2 = 0.f;
#pragma unroll
        for (int k = 0; k < 16; ++k) { smv += sm->red[t][k]; s2 += sm->red2[t][k]; }
        const float m = smv * (1.f / 256.f);
        sm->mean_[t] = m;
        sm->rstd_[t] = rsqrtf(s2 * (1.f / 256.f) - m * m + LEPS);
      }
      __syncthreads();
      const float gd = p.tkmg[i * 256 + t], bd = p.tkmb[i * 256 + t];
      float v[16], out[16];
#pragma unroll
      for (int pp = 0; pp < 16; ++pp) {
        v[pp] = (sm->tile[pp][t] - sm->mean_[pp]) * sm->rstd_[pp] * gd + bd;
        out[pp] = b2[pp];
      }
      for (int e = 0; e < 64; ++e) {
        float acc = b1[e];
#pragma unroll
        for (int pp = 0; pp < 16; ++pp) acc += v[pp] * sm->W1s[pp * 64 + e];
        const float ge = gelu_t(acc);
#pragma unroll
        for (int pp = 0; pp < 16; ++pp) out[pp] += ge * sm->W2s[e * 16 + pp];
      }
#pragma unroll
      for (int pp = 0; pp < 16; ++pp) h[base + pp * 256 + t] = sm->tile[pp][t] + out[pp];
    }
    gbar(p.cnt, 128u * (pb + 1), t);

    // =============== Stage C: channel SRWM (barrier-free) + mixer ========
    {
      SM_C* sm = (SM_C*)smraw;
      const float* Wy0 = p.chWy + i * 4096;
      const float* Wq0 = p.chWq + i * 4096;
      const float* Wk0 = p.chWk + i * 4096;
      const float* wb0 = p.chwb + i * 1024;
      const float* W1 = p.chmW1 + i * 32768;
      const float* b1 = p.chmb1 + i * 128;
      const float* W2 = p.chmW2 + i * 32768;
      const float* b2 = p.chmb2 + i * 256;
      const int hh = t >> 4, r = t & 15;
      const int bp = bid;
      {
        float wy[16], wq[16], wk[16], wbr[16];
#pragma unroll
        for (int j = 0; j < 16; ++j) {
          wy[j]  = Wy0[(hh * 16 + r) * 16 + j];
          wq[j]  = Wq0[(hh * 16 + r) * 16 + j];
          wk[j]  = Wk0[(hh * 16 + r) * 16 + j];
          wbr[j] = wb0[(hh * 4 + (r & 3)) * 16 + j];
        }
        float xp[16];
#pragma unroll
        for (int s = 0; s < 16; ++s)
          xp[s] = h[(size_t)(s * cB * cP + bp) * cD + t];
        // recurrence: ZERO barriers; y streamed to LDS, LN deferred
        for (int s = 0; s < cS; ++s) {
          const float xv = xp[s];
          float y = 0.f, q = 0.f, k = 0.f, bt = 0.f;
#pragma unroll
          for (int j = 0; j < 16; ++j) {
            const float xj = __shfl(xv, j, 16);
            y += wy[j] * xj; q += wq[j] * xj; k += wk[j] * xj; bt += wbr[j] * xj;
          }
          sm->yout[s][t] = y;
          const float bsig = sigm(bt);
          const float eq = __expf(q), ek = __expf(k);
          float ay = 0.f, vyk = 0.f, vqq = 0.f, vqk = 0.f, vkq = 0.f, vkk = 0.f, vbq = 0.f, vbk = 0.f;
          float ksj[16];
#pragma unroll
          for (int j = 0; j < 16; ++j) {
            const float qj = __shfl(eq, j, 16);
            const float kj = __shfl(ek, j, 16);
            ksj[j] = kj;
            ay  += wy[j]  * qj; vyk += wy[j]  * kj;
            vqq += wq[j]  * qj; vqk += wq[j]  * kj;
            vkq += wk[j]  * qj; vkk += wk[j]  * kj;
            vbq += wbr[j] * qj; vbk += wbr[j] * kj;
          }
          const float rq = frcp(row_sum16(eq));
          const float rk = frcp(row_sum16(ek));
          const float ea = __expf(ay * rq);
          const float vyq = ea * frcp(row_sum16(ea));
          const float b0  = __shfl(bsig, 0, 16);
          const float b1v = __shfl(bsig, 1, 16);
          const float b2v = __shfl(bsig, 2, 16);
          const float b3v = __shfl(bsig, 3, 16);
          const float cy = b0  * (vyq      - vyk * rk) * rk;
          const float cq = b1v * (vqq * rq - vqk * rk) * rk;
          const float ck = b2v * (vkq * rq - vkk * rk) * rk;
          const float cb = b3v * (vbq * rq - vbk * rk) * rk;
#pragma unroll
          for (int j = 0; j < 16; ++j) {
            wy[j] += cy * ksj[j]; wq[j] += cq * ksj[j]; wk[j] += ck * ksj[j]; wbr[j] += cb * ksj[j];
          }
        }
      }
      __syncthreads();
      // epilogue: LN(chlng) then mixer LN+FFN, per-row 32-lane groups
      {
        const int r32 = t >> 5, l = t & 31;
        const float4 eg0 = ((const float4*)(p.chlng + i * 256))[l * 2];
        const float4 eg1 = ((const float4*)(p.chlng + i * 256))[l * 2 + 1];
        const float4 eb0 = ((const float4*)(p.chlnb + i * 256))[l * 2];
        const float4 eb1 = ((const float4*)(p.chlnb + i * 256))[l * 2 + 1];
        const float4 mg0 = ((const float4*)(p.chmg + i * 256))[l * 2];
        const float4 mg1 = ((const float4*)(p.chmg + i * 256))[l * 2 + 1];
        const float4 mb0 = ((const float4*)(p.chmb + i * 256))[l * 2];
        const float4 mb1 = ((const float4*)(p.chmb + i * 256))[l * 2 + 1];
        for (int grp = 0; grp < 2; ++grp) {
          const int srow = grp * 8 + r32;
          const float4 y0 = ((const float4*)sm->yout[srow])[l * 2];
          const float4 y1 = ((const float4*)sm->yout[srow])[l * 2 + 1];
          float s1 = y0.x + y0.y + y0.z + y0.w + y1.x + y1.y + y1.z + y1.w;
          float s2 = y0.x * y0.x + y0.y * y0.y + y0.z * y0.z + y0.w * y0.w +
                     y1.x * y1.x + y1.y * y1.y + y1.z * y1.z + y1.w * y1.w;
#pragma unroll
          for (int o = 1; o < 32; o <<= 1) {
            s1 += __shfl_xor(s1, o, 32);
            s2 += __shfl_xor(s2, o, 32);
          }
          const float m1 = s1 * (1.f / 256.f);
          const float rst1 = rsqrtf(s2 * (1.f / 256.f) - m1 * m1 + LEPS);
          float4 a0, a1;
          a0.x = (y0.x - m1) * rst1 * eg0.x + eb0.x; a0.y = (y0.y - m1) * rst1 * eg0.y + eb0.y;
          a0.z = (y0.z - m1) * rst1 * eg0.z + eb0.z; a0.w = (y0.w - m1) * rst1 * eg0.w + eb0.w;
          a1.x = (y1.x - m1) * rst1 * eg1.x + eb1.x; a1.y = (y1.y - m1) * rst1 * eg1.y + eb1.y;
          a1.z = (y1.z - m1) * rst1 * eg1.z + eb1.z; a1.w = (y1.w - m1) * rst1 * eg1.w + eb1.w;
          float u1 = a0.x + a0.y + a0.z + a0.w + a1.x + a1.y + a1.z + a1.w;
          float u2 = a0.x * a0.x + a0.y * a0.y + a0.z * a0.z + a0.w * a0.w +
                     a1.x * a1.x + a1.y * a1.y + a1.z * a1.z + a1.w * a1.w;
#pragma unroll
          for (int o = 1; o < 32; o <<= 1) {
            u1 += __shfl_xor(u1, o, 32);
            u2 += __shfl_xor(u2, o, 32);
          }
          const float m2 = u1 * (1.f / 256.f);
          const float rst2 = rsqrtf(u2 * (1.f / 256.f) - m2 * m2 + LEPS);
          float4 L0, L1;
          L0.x = (a0.x - m2) * rst2 * mg0.x + mb0.x; L0.y = (a0.y - m2) * rst2 * mg0.y + mb0.y;
          L0.z = (a0.z - m2) * rst2 * mg0.z + mb0.z; L0.w = (a0.w - m2) * rst2 * mg0.w + mb0.w;
          L1.x = (a1.x - m2) * rst2 * mg1.x + mb1.x; L1.y = (a1.y - m2) * rst2 * mg1.y + mb1.y;
          L1.z = (a1.z - m2) * rst2 * mg1.z + mb1.z; L1.w = (a1.w - m2) * rst2 * mg1.w + mb1.w;
          ((float4*)sm->lnv[r32])[l * 2]     = L0;
          ((float4*)sm->lnv[r32])[l * 2 + 1] = L1;
          __syncthreads();
          {
            const float4* W1f = (const float4*)W1;
            float4 acc = ((const float4*)b1)[l];
            for (int j = 0; j < 256; ++j) {
              const float xj = sm->lnv[r32][j];
              const float4 wv = W1f[j * 32 + l];
              acc.x += xj * wv.x; acc.y += xj * wv.y; acc.z += xj * wv.z; acc.w += xj * wv.w;
            }
            float4 hv;
            hv.x = gelu_t(acc.x); hv.y = gelu_t(acc.y);
            hv.z = gelu_t(acc.z); hv.w = gelu_t(acc.w);
            ((float4*)sm->hid[r32])[l] = hv;
          }
          __syncthreads();
          {
            const float4* W2f = (const float4*)W2;
            float4 o0 = ((const float4*)b2)[l * 2];
            float4 o1 = ((const float4*)b2)[l * 2 + 1];
            for (int e = 0; e < 128; ++e) {
              const float xh = sm->hid[r32][e];
              const float4 w0 = W2f[e * 64 + l * 2];
              const float4 w1 = W2f[e * 64 + l * 2 + 1];
              o0.x += xh * w0.x; o0.y += xh * w0.y; o0.z += xh * w0.z; o0.w += xh * w0.w;
              o1.x += xh * w1.x; o1.y += xh * w1.y; o1.z += xh * w1.z; o1.w += xh * w1.w;
            }
            o0.x += a0.x; o0.y += a0.y; o0.z += a0.z; o0.w += a0.w;
            o1.x += a1.x; o1.y += a1.y; o1.z += a1.z; o1.w += a1.w;
            float4* op = (float4*)(h + (size_t)(srow * cB * cP + bp) * cD);
            op[l * 2]     = o0;
            op[l * 2 + 1] = o1;
          }
          __syncthreads();
        }
      }
    }
    gbar(p.cnt, 128u * (pb + 2), t);
  }

  // ================= Stage F: final LN + mean (block = sb) ================
  {
    SM_F* sm = (SM_F*)smraw;
    const int sb = bid;
    const float4 g4 = ((const float4*)p.flng)[lane];
    const float4 b4 = ((const float4*)p.flnb)[lane];
    float a0 = 0.f, a1 = 0.f, a2 = 0.f, a3 = 0.f;
    for (int pp = 0; pp < 4; ++pp) {
      const int pch = w * 4 + pp;
      const float4 v4 = ((const float4*)(h + ((size_t)sb * cP + pch) * cD))[lane];
      const float s1 = wave_sum64(v4.x + v4.y + v4.z + v4.w);
      const float s2 = wave_sum64(v4.x * v4.x + v4.y * v4.y + v4.z * v4.z + v4.w * v4.w);
      const float m = s1 * (1.f / 256.f);
      const float rst = rsqrtf(s2 * (1.f / 256.f) - m * m + LEPS);
      a0 += (v4.x - m) * rst * g4.x + b4.x;
      a1 += (v4.y - m) * rst * g4.y + b4.y;
      a2 += (v4.z - m) * rst * g4.z + b4.z;
      a3 += (v4.w - m) * rst * g4.w + b4.w;
    }
    ((float4*)sm->sacc[w])[lane] = make_float4(a0, a1, a2, a3);
    __syncthreads();
    p.gbuf[(size_t)sb * cD + t] =
        (sm->sacc[0][t] + sm->sacc[1][t] + sm->sacc[2][t] + sm->sacc[3][t]) * (1.f / 16.f);
  }
  gbar(p.cnt, 128u * 8, t);

  // ================= Stage O: output SRWM + projection (blocks 0..7) ======
  if (bid < cB) {
    SM_O* sm = (SM_O*)smraw;
    const int hh = t >> 4, r = t & 15;
    const int b = bid;
    float wy[16], wq[16], wk[16], wbr[16];
#pragma unroll
    for (int j = 0; j < 16; ++j) {
      wy[j]  = p.oWy[(hh * 16 + r) * 16 + j];
      wq[j]  = p.oWq[(hh * 16 + r) * 16 + j];
      wk[j]  = p.oWk[(hh * 16 + r) * 16 + j];
      wbr[j] = p.owb[(hh * 4 + (r & 3)) * 16 + j];
    }
    // projection constants: gwm[c][t] in LDS; Gc,Bc block sums
    {
      const float gg = p.olng[t], bbl = p.olnb[t];
      float pg[cNC], pbv[cNC];
#pragma unroll
      for (int c = 0; c < cNC; ++c) {
        const float wv = p.outW[(size_t)t * cNC + c];
        const float gwv = gg * wv;
        sm->gwm[c][t] = gwv;
        pg[c] = wave_sum64(gwv);
        pbv[c] = wave_sum64(bbl * wv);
      }
      if (lane == 0) {
#pragma unroll
        for (int c = 0; c < cNC; ++c) { sm->GBp[w][c] = pg[c]; sm->GBp[w][5 + c] = pbv[c]; }
      }
      __syncthreads();
      if (t < 10) sm->GBs[t] = sm->GBp[0][t] + sm->GBp[1][t] + sm->GBp[2][t] + sm->GBp[3][t];
      __syncthreads();
    }
    float xp[16];
#pragma unroll
    for (int s = 0; s < 16; ++s) xp[s] = p.gbuf[(size_t)(s * cB + b) * cD + t];
    // recurrence, barrier-free; y streamed to LDS
    for (int s = 0; s < cS; ++s) {
      const float xv = xp[s];
      float y = 0.f, q = 0.f, k = 0.f, bt = 0.f;
#pragma unroll
      for (int j = 0; j < 16; ++j) {
        const float xj = __shfl(xv, j, 16);
        y += wy[j] * xj; q += wq[j] * xj; k += wk[j] * xj; bt += wbr[j] * xj;
      }
      sm->ymat[s][t] = y;
      const float bsig = sigm(bt);
      const float eq = __expf(q), ek = __expf(k);
      float ay = 0.f, vyk = 0.f, vqq = 0.f, vqk = 0.f, vkq = 0.f, vkk = 0.f, vbq = 0.f, vbk = 0.f;
      float ksj[16];
#pragma unroll
      for (int j = 0; j < 16; ++j) {
        const float qj = __shfl(eq, j, 16);
        const float kj = __shfl(ek, j, 16);
        ksj[j] = kj;
        ay  += wy[j]  * qj; vyk += wy[j]  * kj;
        vqq += wq[j]  * qj; vqk += wq[j]  * kj;
        vkq += wk[j]  * qj; vkk += wk[j]  * kj;
        vbq += wbr[j] * qj; vbk += wbr[j] * kj;
      }
      const float rq = frcp(row_sum16(eq));
      const float rk = frcp(row_sum16(ek));
      const float ea = __expf(ay * rq);
      const float vyq = ea * frcp(row_sum16(ea));
      const float b0  = __shfl(bsig, 0, 16);
      const float b1v = __shfl(bsig, 1, 16);
      const float b2v = __shfl(bsig, 2, 16);
      const float b3v = __shfl(bsig, 3, 16);
      const float cy = b0  * (vyq      - vyk * rk) * rk;
      const float cq = b1v * (vqq * rq - vqk * rk) * rk;
      const float ck = b2v * (vkq * rq - vkk * rk) * rk;
      const float cb = b3v * (vbq * rq - vbk * rk) * rk;
#pragma unroll
      for (int j = 0; j < 16; ++j) {
        wy[j] += cy * ksj[j]; wq[j] += cq * ksj[j]; wk[j] += ck * ksj[j]; wbr[j] += cb * ksj[j];
      }
    }
    __syncthreads();
    // batched LN + projection: wave w handles steps 4w..4w+3
    for (int k2 = 0; k2 < 4; ++k2) {
      const int sidx = w * 4 + k2;
      const float4 y4 = ((const float4*)sm->ymat[sidx])[lane];
      const float s1 = wave_sum64(y4.x + y4.y + y4.z + y4.w);
      const float s2 = wave_sum64(y4.x * y4.x + y4.y * y4.y + y4.z * y4.z + y4.w * y4.w);
      float S[cNC];
#pragma unroll
      for (int c = 0; c < cNC; ++c) {
        const float4 g4 = ((const float4*)sm->gwm[c])[lane];
        S[c] = wave_sum64(y4.x * g4.x + y4.y * g4.y + y4.z * g4.z + y4.w * g4.w);
      }
      if (lane == 0) {
        const float m = s1 * (1.f / 256.f);
        const float var = s2 * (1.f / 256.f) - m * m;
        const float rst = rsqrtf(var + LEPS);
#pragma unroll
        for (int c = 0; c < cNC; ++c) {
          p.outp[(size_t)(sidx * cB + b) * cNC + c] =
              p.outb[c] + rst * S[c] - rst * m * sm->GBs[c] + sm->GBs[5 + c];
        }
      }
    }
  }
}

extern "C" void kernel_launch(void* const* d_in, const int* in_sizes, int n_in,
                              void* d_out, int out_size, void* d_ws, size_t ws_size,
                              hipStream_t stream) {
  Params prm;
  prm.x     = (const float*)d_in[0];
  prm.fb    = (const int*)d_in[1];
  prm.inW   = (const float*)d_in[2];
  prm.inb   = (const float*)d_in[3];
  prm.tkWy  = (const float*)d_in[4];
  prm.tkWq  = (const float*)d_in[5];
  prm.tkWk  = (const float*)d_in[6];
  prm.tkwb  = (const float*)d_in[7];
  prm.tklng = (const float*)d_in[8];
  prm.tklnb = (const float*)d_in[9];
  prm.tkmg  = (const float*)d_in[10];
  prm.tkmb  = (const float*)d_in[11];
  prm.tkmW1 = (const float*)d_in[12];
  prm.tkmb1 = (const float*)d_in[13];
  prm.tkmW2 = (const float*)d_in[14];
  prm.tkmb2 = (const float*)d_in[15];
  prm.chWy  = (const float*)d_in[16];
  prm.chWq  = (const float*)d_in[17];
  prm.chWk  = (const float*)d_in[18];
  prm.chwb  = (const float*)d_in[19];
  prm.chlng = (const float*)d_in[20];
  prm.chlnb = (const float*)d_in[21];
  prm.chmg  = (const float*)d_in[22];
  prm.chmb  = (const float*)d_in[23];
  prm.chmW1 = (const float*)d_in[24];
  prm.chmb1 = (const float*)d_in[25];
  prm.chmW2 = (const float*)d_in[26];
  prm.chmb2 = (const float*)d_in[27];
  prm.flng  = (const float*)d_in[28];
  prm.flnb  = (const float*)d_in[29];
  prm.oWy   = (const float*)d_in[30];
  prm.oWq   = (const float*)d_in[31];
  prm.oWk   = (const float*)d_in[32];
  prm.owb   = (const float*)d_in[33];
  prm.olng  = (const float*)d_in[34];
  prm.olnb  = (const float*)d_in[35];
  prm.outW  = (const float*)d_in[36];
  prm.outb  = (const float*)d_in[37];
  prm.h     = (float*)d_ws;
  prm.gbuf  = prm.h + (size_t)cS * cB * cP * cD;
  prm.cnt   = (unsigned*)(prm.gbuf + (size_t)cS * cB * cD);
  prm.outp  = (float*)d_out;

  hipMemsetAsync((void*)prm.cnt, 0, 64, stream);
  k_fused<<<dim3(128), dim3(256), 0, stream>>>(prm);
}

// Round 10
// 333.958 us; speedup vs baseline: 2.1164x; 2.1164x over previous
//
#include <hip/hip_runtime.h>
#include <math.h>

// Problem constants (from reference)
constexpr int cS  = 16;   // sequence
constexpr int cB  = 8;    // batch
constexpr int cNC = 5;    // classes
constexpr int cD  = 256;  // hidden
constexpr int cP  = 16;   // patches
constexpr int cPD = 49;   // patch dim
#define LEPS 1e-5f

__device__ __forceinline__ float frcp(float x) { return __builtin_amdgcn_rcpf(x); }
__device__ __forceinline__ float sigm(float x) { return frcp(1.0f + __expf(-x)); }
// gelu(tanh approx) == x * sigmoid(1.5957691*(x+0.044715x^3)*2/... ) exact identity
__device__ __forceinline__ float gelu_t(float x) {
  const float z = 1.5957691216057308f * (x + 0.044715f * x * x * x);
  return x * frcp(1.0f + __expf(-z));
}

// ---- DPP 16-lane reductions
template<int CTRL>
__device__ __forceinline__ float dpp_mov(float v) {
  return __int_as_float(__builtin_amdgcn_update_dpp(
      0, __float_as_int(v), CTRL, 0xF, 0xF, true));
}
__device__ __forceinline__ float row_sum16(float v) {
  v += dpp_mov<0xB1>(v);   // quad_perm [1,0,3,2]
  v += dpp_mov<0x4E>(v);   // quad_perm [2,3,0,1]
  v += dpp_mov<0x124>(v);  // row_ror:4
  v += dpp_mov<0x128>(v);  // row_ror:8
  return v;
}
__device__ __forceinline__ float wave_sum64(float v) {
  v = row_sum16(v);
  v += __shfl_xor(v, 16, 64);
  v += __shfl_xor(v, 32, 64);
  return v;
}

// ---------------- embed: patchify + one-hot concat + linear ----------------
__global__ __launch_bounds__(256) void k_embed(const float* __restrict__ x,
                                               const int* __restrict__ fb,
                                               const float* __restrict__ inW,
                                               const float* __restrict__ inb,
                                               float* __restrict__ h) {
  const int blk = blockIdx.x;
  const int p  = blk & 15;
  const int sb = blk >> 4;
  const int ph = p >> 2, pw = p & 3;
  __shared__ float sx[cPD];
  const int t = threadIdx.x;
  if (t < cPD) {
    const int p1 = t / 7, p2 = t % 7;
    sx[t] = x[(size_t)sb * 784 + (ph * 7 + p1) * 28 + (pw * 7 + p2)];
  }
  __syncthreads();
  const int cls = fb[sb];
  float acc = inb[t] + inW[(size_t)(cPD + cls) * cD + t];
#pragma unroll
  for (int j = 0; j < cPD; ++j) acc += sx[j] * inW[(size_t)j * cD + t];
  h[((size_t)sb * cP + p) * cD + t] = acc;
}

// ---------------- token SRWM: wave-centric, DPP + deferred-normalize -------
__global__ __launch_bounds__(256) void k_tok_srwm(
    float* __restrict__ h, const float* __restrict__ Wy0, const float* __restrict__ Wq0,
    const float* __restrict__ Wk0, const float* __restrict__ wb0,
    const float* __restrict__ lng, const float* __restrict__ lnb) {
  const int t    = threadIdx.x;
  const int lane = t & 63;
  const int w    = t >> 6;
  const int r    = lane & 15;
  const int li   = lane >> 4;
  const int b    = blockIdx.x >> 4;
  const int d    = ((blockIdx.x & 15) << 4) + (w << 2) + li;
  float wy[16], wq[16], wk[16], wbr[16];
#pragma unroll
  for (int j = 0; j < 16; ++j) {
    wy[j]  = Wy0[r * 16 + j];
    wq[j]  = Wq0[r * 16 + j];
    wk[j]  = Wk0[r * 16 + j];
    wbr[j] = wb0[(r & 3) * 16 + j];
  }
  const float gg = lng[r], bb = lnb[r];
  float xp[16];
#pragma unroll
  for (int s = 0; s < 16; ++s)
    xp[s] = h[((size_t)(s * cB + b) * cP + r) * cD + d];
  for (int s = 0; s < cS; ++s) {
    const float xv = xp[s];
    float y = 0.f, q = 0.f, k = 0.f, bt = 0.f;
#pragma unroll
    for (int j = 0; j < 16; ++j) {
      const float xj = __shfl(xv, j, 16);
      y += wy[j] * xj; q += wq[j] * xj; k += wk[j] * xj; bt += wbr[j] * xj;
    }
    const float bsig = sigm(bt);
    const float eq = __expf(q), ek = __expf(k);
    float ay = 0.f, vyk = 0.f, vqq = 0.f, vqk = 0.f, vkq = 0.f, vkk = 0.f, vbq = 0.f, vbk = 0.f;
    float ksj[16];
#pragma unroll
    for (int j = 0; j < 16; ++j) {
      const float qj = __shfl(eq, j, 16);
      const float kj = __shfl(ek, j, 16);
      ksj[j] = kj;
      ay  += wy[j]  * qj; vyk += wy[j]  * kj;
      vqq += wq[j]  * qj; vqk += wq[j]  * kj;
      vkq += wk[j]  * qj; vkk += wk[j]  * kj;
      vbq += wbr[j] * qj; vbk += wbr[j] * kj;
    }
    const float rq = frcp(row_sum16(eq));
    const float rk = frcp(row_sum16(ek));
    const float ea = __expf(ay * rq);
    const float vyq = ea * frcp(row_sum16(ea));
    const float b0  = __shfl(bsig, 0, 16);
    const float b1v = __shfl(bsig, 1, 16);
    const float b2v = __shfl(bsig, 2, 16);
    const float b3v = __shfl(bsig, 3, 16);
    const float cy = b0  * (vyq      - vyk * rk) * rk;
    const float cq = b1v * (vqq * rq - vqk * rk) * rk;
    const float ck = b2v * (vkq * rq - vkk * rk) * rk;
    const float cb = b3v * (vbq * rq - vbk * rk) * rk;
#pragma unroll
    for (int j = 0; j < 16; ++j) {
      wy[j] += cy * ksj[j]; wq[j] += cq * ksj[j]; wk[j] += ck * ksj[j]; wbr[j] += cb * ksj[j];
    }
    const float s1 = row_sum16(y);
    const float s2 = row_sum16(y * y);
    const float m = s1 * 0.0625f;
    const float var = s2 * 0.0625f - m * m;
    h[((size_t)(s * cB + b) * cP + r) * cD + d] = (y - m) * rsqrtf(var + LEPS) * gg + bb;
  }
}

// ---------------- token mixer: LN(D) then FFN over patch axis --------------
__global__ __launch_bounds__(256) void k_tok_mixer(
    float* __restrict__ h, const float* __restrict__ g, const float* __restrict__ bta,
    const float* __restrict__ W1, const float* __restrict__ b1,
    const float* __restrict__ W2, const float* __restrict__ b2) {
  const int sb = blockIdx.x;
  const int t = threadIdx.x;
  __shared__ float tile[16][256];
  __shared__ float W1s[16 * 64], W2s[64 * 16];
  __shared__ float mean_[16], rstd_[16];
  __shared__ float red[16][17], red2[16][17];
  const size_t base = (size_t)sb * cP * cD;
#pragma unroll
  for (int p = 0; p < 16; ++p) tile[p][t] = h[base + p * 256 + t];
  W1s[t] = W1[t]; W1s[t + 256] = W1[t + 256]; W1s[t + 512] = W1[t + 512]; W1s[t + 768] = W1[t + 768];
  W2s[t] = W2[t]; W2s[t + 256] = W2[t + 256]; W2s[t + 512] = W2[t + 512]; W2s[t + 768] = W2[t + 768];
  __syncthreads();
  const int p = t >> 4, l = t & 15;
  float ps = 0.f, ps2 = 0.f;
#pragma unroll
  for (int k = 0; k < 16; ++k) { const float v = tile[p][l + 16 * k]; ps += v; ps2 += v * v; }
  red[p][l] = ps; red2[p][l] = ps2;
  __syncthreads();
  if (t < 16) {
    float sm = 0.f, s2 = 0.f;
#pragma unroll
    for (int k = 0; k < 16; ++k) { sm += red[t][k]; s2 += red2[t][k]; }
    const float m = sm * (1.f / 256.f);
    mean_[t] = m;
    rstd_[t] = rsqrtf(s2 * (1.f / 256.f) - m * m + LEPS);
  }
  __syncthreads();
  const float gd = g[t], bd = bta[t];
  float v[16], out[16];
#pragma unroll
  for (int pp = 0; pp < 16; ++pp) {
    v[pp] = (tile[pp][t] - mean_[pp]) * rstd_[pp] * gd + bd;
    out[pp] = b2[pp];
  }
  for (int e = 0; e < 64; ++e) {
    float acc = b1[e];
#pragma unroll
    for (int pp = 0; pp < 16; ++pp) acc += v[pp] * W1s[pp * 64 + e];
    const float ge = gelu_t(acc);
#pragma unroll
    for (int pp = 0; pp < 16; ++pp) out[pp] += ge * W2s[e * 16 + pp];
  }
#pragma unroll
  for (int pp = 0; pp < 16; ++pp) h[base + pp * 256 + t] = tile[pp][t] + out[pp];
}

// ------- channel SRWM (BARRIER-FREE scan) + fused LN + channel mixer -------
// Recurrence state update needs only per-head q,k,beta -> intra-16-lane.
// Raw y streamed to LDS; both LNs + FFN run as a batched epilogue.
__global__ __launch_bounds__(256, 1) void k_ch_srwm_mix(
    float* __restrict__ h, const float* __restrict__ Wy0, const float* __restrict__ Wq0,
    const float* __restrict__ Wk0, const float* __restrict__ wb0,
    const float* __restrict__ lng, const float* __restrict__ lnb,
    const float* __restrict__ mg, const float* __restrict__ mb,
    const float* __restrict__ W1, const float* __restrict__ b1,
    const float* __restrict__ W2, const float* __restrict__ b2) {
  const int t = threadIdx.x;
  const int hh = t >> 4, r = t & 15;
  const int bp = blockIdx.x;
  __shared__ float yout[16][256];
  __shared__ float lnv[8][256];
  __shared__ float hid[8][128];
  {
    float wy[16], wq[16], wk[16], wbr[16];
#pragma unroll
    for (int j = 0; j < 16; ++j) {
      wy[j]  = Wy0[(hh * 16 + r) * 16 + j];
      wq[j]  = Wq0[(hh * 16 + r) * 16 + j];
      wk[j]  = Wk0[(hh * 16 + r) * 16 + j];
      wbr[j] = wb0[(hh * 4 + (r & 3)) * 16 + j];
    }
    float xp[16];
#pragma unroll
    for (int s = 0; s < 16; ++s)
      xp[s] = h[(size_t)(s * cB * cP + bp) * cD + t];
    for (int s = 0; s < cS; ++s) {
      const float xv = xp[s];
      float y = 0.f, q = 0.f, k = 0.f, bt = 0.f;
#pragma unroll
      for (int j = 0; j < 16; ++j) {
        const float xj = __shfl(xv, j, 16);
        y += wy[j] * xj; q += wq[j] * xj; k += wk[j] * xj; bt += wbr[j] * xj;
      }
      yout[s][t] = y;               // raw y; LN deferred to epilogue
      const float bsig = sigm(bt);
      const float eq = __expf(q), ek = __expf(k);
      float ay = 0.f, vyk = 0.f, vqq = 0.f, vqk = 0.f, vkq = 0.f, vkk = 0.f, vbq = 0.f, vbk = 0.f;
      float ksj[16];
#pragma unroll
      for (int j = 0; j < 16; ++j) {
        const float qj = __shfl(eq, j, 16);
        const float kj = __shfl(ek, j, 16);
        ksj[j] = kj;
        ay  += wy[j]  * qj; vyk += wy[j]  * kj;
        vqq += wq[j]  * qj; vqk += wq[j]  * kj;
        vkq += wk[j]  * qj; vkk += wk[j]  * kj;
        vbq += wbr[j] * qj; vbk += wbr[j] * kj;
      }
      const float rq = frcp(row_sum16(eq));
      const float rk = frcp(row_sum16(ek));
      const float ea = __expf(ay * rq);
      const float vyq = ea * frcp(row_sum16(ea));
      const float b0  = __shfl(bsig, 0, 16);
      const float b1v = __shfl(bsig, 1, 16);
      const float b2v = __shfl(bsig, 2, 16);
      const float b3v = __shfl(bsig, 3, 16);
      const float cy = b0  * (vyq      - vyk * rk) * rk;
      const float cq = b1v * (vqq * rq - vqk * rk) * rk;
      const float ck = b2v * (vkq * rq - vkk * rk) * rk;
      const float cb = b3v * (vbq * rq - vbk * rk) * rk;
#pragma unroll
      for (int j = 0; j < 16; ++j) {
        wy[j] += cy * ksj[j]; wq[j] += cq * ksj[j]; wk[j] += ck * ksj[j]; wbr[j] += cb * ksj[j];
      }
    }
  }
  __syncthreads();
  // epilogue: LN(chlng/chlnb) then mixer LN + FFN; 32 lanes per row
  {
    const int r32 = t >> 5, l = t & 31;
    const float4 eg0 = ((const float4*)lng)[l * 2];
    const float4 eg1 = ((const float4*)lng)[l * 2 + 1];
    const float4 eb0 = ((const float4*)lnb)[l * 2];
    const float4 eb1 = ((const float4*)lnb)[l * 2 + 1];
    const float4 mg0 = ((const float4*)mg)[l * 2];
    const float4 mg1 = ((const float4*)mg)[l * 2 + 1];
    const float4 mb0 = ((const float4*)mb)[l * 2];
    const float4 mb1 = ((const float4*)mb)[l * 2 + 1];
    for (int grp = 0; grp < 2; ++grp) {
      const int srow = grp * 8 + r32;
      const float4 y0 = ((const float4*)yout[srow])[l * 2];
      const float4 y1 = ((const float4*)yout[srow])[l * 2 + 1];
      float s1 = y0.x + y0.y + y0.z + y0.w + y1.x + y1.y + y1.z + y1.w;
      float s2 = y0.x * y0.x + y0.y * y0.y + y0.z * y0.z + y0.w * y0.w +
                 y1.x * y1.x + y1.y * y1.y + y1.z * y1.z + y1.w * y1.w;
#pragma unroll
      for (int o = 1; o < 32; o <<= 1) {
        s1 += __shfl_xor(s1, o, 32);
        s2 += __shfl_xor(s2, o, 32);
      }
      const float m1 = s1 * (1.f / 256.f);
      const float rst1 = rsqrtf(s2 * (1.f / 256.f) - m1 * m1 + LEPS);
      float4 a0, a1;   // SRWM output after its LN (the residual input)
      a0.x = (y0.x - m1) * rst1 * eg0.x + eb0.x; a0.y = (y0.y - m1) * rst1 * eg0.y + eb0.y;
      a0.z = (y0.z - m1) * rst1 * eg0.z + eb0.z; a0.w = (y0.w - m1) * rst1 * eg0.w + eb0.w;
      a1.x = (y1.x - m1) * rst1 * eg1.x + eb1.x; a1.y = (y1.y - m1) * rst1 * eg1.y + eb1.y;
      a1.z = (y1.z - m1) * rst1 * eg1.z + eb1.z; a1.w = (y1.w - m1) * rst1 * eg1.w + eb1.w;
      float u1 = a0.x + a0.y + a0.z + a0.w + a1.x + a1.y + a1.z + a1.w;
      float u2 = a0.x * a0.x + a0.y * a0.y + a0.z * a0.z + a0.w * a0.w +
                 a1.x * a1.x + a1.y * a1.y + a1.z * a1.z + a1.w * a1.w;
#pragma unroll
      for (int o = 1; o < 32; o <<= 1) {
        u1 += __shfl_xor(u1, o, 32);
        u2 += __shfl_xor(u2, o, 32);
      }
      const float m2 = u1 * (1.f / 256.f);
      const float rst2 = rsqrtf(u2 * (1.f / 256.f) - m2 * m2 + LEPS);
      float4 L0, L1;
      L0.x = (a0.x - m2) * rst2 * mg0.x + mb0.x; L0.y = (a0.y - m2) * rst2 * mg0.y + mb0.y;
      L0.z = (a0.z - m2) * rst2 * mg0.z + mb0.z; L0.w = (a0.w - m2) * rst2 * mg0.w + mb0.w;
      L1.x = (a1.x - m2) * rst2 * mg1.x + mb1.x; L1.y = (a1.y - m2) * rst2 * mg1.y + mb1.y;
      L1.z = (a1.z - m2) * rst2 * mg1.z + mb1.z; L1.w = (a1.w - m2) * rst2 * mg1.w + mb1.w;
      ((float4*)lnv[r32])[l * 2]     = L0;
      ((float4*)lnv[r32])[l * 2 + 1] = L1;
      __syncthreads();
      {
        const float4* W1f = (const float4*)W1;
        float4 acc = ((const float4*)b1)[l];
        for (int j = 0; j < 256; ++j) {
          const float xj = lnv[r32][j];
          const float4 wv = W1f[j * 32 + l];
          acc.x += xj * wv.x; acc.y += xj * wv.y; acc.z += xj * wv.z; acc.w += xj * wv.w;
        }
        float4 hv;
        hv.x = gelu_t(acc.x); hv.y = gelu_t(acc.y);
        hv.z = gelu_t(acc.z); hv.w = gelu_t(acc.w);
        ((float4*)hid[r32])[l] = hv;
      }
      __syncthreads();
      {
        const float4* W2f = (const float4*)W2;
        float4 o0 = ((const float4*)b2)[l * 2];
        float4 o1 = ((const float4*)b2)[l * 2 + 1];
        for (int e = 0; e < 128; ++e) {
          const float xh = hid[r32][e];
          const float4 w0 = W2f[e * 64 + l * 2];
          const float4 w1 = W2f[e * 64 + l * 2 + 1];
          o0.x += xh * w0.x; o0.y += xh * w0.y; o0.z += xh * w0.z; o0.w += xh * w0.w;
          o1.x += xh * w1.x; o1.y += xh * w1.y; o1.z += xh * w1.z; o1.w += xh * w1.w;
        }
        o0.x += a0.x; o0.y += a0.y; o0.z += a0.z; o0.w += a0.w;
        o1.x += a1.x; o1.y += a1.y; o1.z += a1.z; o1.w += a1.w;
        float4* op = (float4*)(h + (size_t)(srow * cB * cP + bp) * cD);
        op[l * 2]     = o0;
        op[l * 2 + 1] = o1;
      }
      __syncthreads();
    }
  }
}

// ---------------- final LN + mean over patches -----------------------------
__global__ __launch_bounds__(256) void k_fln_mean(
    const float* __restrict__ h, const float* __restrict__ gg, const float* __restrict__ bbv,
    float* __restrict__ o) {
  const int sb = blockIdx.x;
  const int t = threadIdx.x;
  const int lane = t & 63, w = t >> 6;
  const float4 g4 = ((const float4*)gg)[lane];
  const float4 b4 = ((const float4*)bbv)[lane];
  float a0 = 0.f, a1 = 0.f, a2 = 0.f, a3 = 0.f;
  for (int pp = 0; pp < 4; ++pp) {
    const int p = w * 4 + pp;
    const float4 v4 = ((const float4*)(h + ((size_t)sb * cP + p) * cD))[lane];
    const float s1 = wave_sum64(v4.x + v4.y + v4.z + v4.w);
    const float s2 = wave_sum64(v4.x * v4.x + v4.y * v4.y + v4.z * v4.z + v4.w * v4.w);
    const float m = s1 * (1.f / 256.f);
    const float rst = rsqrtf(s2 * (1.f / 256.f) - m * m + LEPS);
    a0 += (v4.x - m) * rst * g4.x + b4.x;
    a1 += (v4.y - m) * rst * g4.y + b4.y;
    a2 += (v4.z - m) * rst * g4.z + b4.z;
    a3 += (v4.w - m) * rst * g4.w + b4.w;
  }
  __shared__ float sacc[4][256];
  float4* sp = (float4*)sacc[w];
  sp[lane] = make_float4(a0, a1, a2, a3);
  __syncthreads();
  o[(size_t)sb * cD + t] = (sacc[0][t] + sacc[1][t] + sacc[2][t] + sacc[3][t]) * (1.f / 16.f);
}

// -------- output SRWM: BARRIER-FREE scan + batched LN/projection ----------
// Projection by linearity: sum_t lnt*w = rst*S1c - rst*m*Gc + Bc.
__global__ __launch_bounds__(256, 1) void k_out_srwm(
    const float* __restrict__ gin, float* __restrict__ outp,
    const float* __restrict__ Wy0, const float* __restrict__ Wq0,
    const float* __restrict__ Wk0, const float* __restrict__ wb0,
    const float* __restrict__ lng, const float* __restrict__ lnb,
    const float* __restrict__ outW, const float* __restrict__ outb) {
  const int t = threadIdx.x;
  const int lane = t & 63;
  const int w = t >> 6;
  const int hh = t >> 4, r = t & 15;
  const int b = blockIdx.x;
  __shared__ float ymat[16][256];
  __shared__ float gwm[cNC][256];
  __shared__ float GBp[4][10];
  __shared__ float GBs[10];
  float wy[16], wq[16], wk[16], wbr[16];
#pragma unroll
  for (int j = 0; j < 16; ++j) {
    wy[j]  = Wy0[(hh * 16 + r) * 16 + j];
    wq[j]  = Wq0[(hh * 16 + r) * 16 + j];
    wk[j]  = Wk0[(hh * 16 + r) * 16 + j];
    wbr[j] = wb0[(hh * 4 + (r & 3)) * 16 + j];
  }
  {
    const float gg = lng[t], bbl = lnb[t];
    float pg[cNC], pbv[cNC];
#pragma unroll
    for (int c = 0; c < cNC; ++c) {
      const float wv = outW[(size_t)t * cNC + c];
      const float gwv = gg * wv;
      gwm[c][t] = gwv;
      pg[c] = wave_sum64(gwv);
      pbv[c] = wave_sum64(bbl * wv);
    }
    if (lane == 0) {
#pragma unroll
      for (int c = 0; c < cNC; ++c) { GBp[w][c] = pg[c]; GBp[w][5 + c] = pbv[c]; }
    }
    __syncthreads();
    if (t < 10) GBs[t] = GBp[0][t] + GBp[1][t] + GBp[2][t] + GBp[3][t];
    __syncthreads();
  }
  float xp[16];
#pragma unroll
  for (int s = 0; s < 16; ++s) xp[s] = gin[(size_t)(s * cB + b) * cD + t];
  for (int s = 0; s < cS; ++s) {
    const float xv = xp[s];
    float y = 0.f, q = 0.f, k = 0.f, bt = 0.f;
#pragma unroll
    for (int j = 0; j < 16; ++j) {
      const float xj = __shfl(xv, j, 16);
      y += wy[j] * xj; q += wq[j] * xj; k += wk[j] * xj; bt += wbr[j] * xj;
    }
    ymat[s][t] = y;
    const float bsig = sigm(bt);
    const float eq = __expf(q), ek = __expf(k);
    float ay = 0.f, vyk = 0.f, vqq = 0.f, vqk = 0.f, vkq = 0.f, vkk = 0.f, vbq = 0.f, vbk = 0.f;
    float ksj[16];
#pragma unroll
    for (int j = 0; j < 16; ++j) {
      const float qj = __shfl(eq, j, 16);
      const float kj = __shfl(ek, j, 16);
      ksj[j] = kj;
      ay  += wy[j]  * qj; vyk += wy[j]  * kj;
      vqq += wq[j]  * qj; vqk += wq[j]  * kj;
      vkq += wk[j]  * qj; vkk += wk[j]  * kj;
      vbq += wbr[j] * qj; vbk += wbr[j] * kj;
    }
    const float rq = frcp(row_sum16(eq));
    const float rk = frcp(row_sum16(ek));
    const float ea = __expf(ay * rq);
    const float vyq = ea * frcp(row_sum16(ea));
    const float b0  = __shfl(bsig, 0, 16);
    const float b1v = __shfl(bsig, 1, 16);
    const float b2v = __shfl(bsig, 2, 16);
    const float b3v = __shfl(bsig, 3, 16);
    const float cy = b0  * (vyq      - vyk * rk) * rk;
    const float cq = b1v * (vqq * rq - vqk * rk) * rk;
    const float ck = b2v * (vkq * rq - vkk * rk) * rk;
    const float cb = b3v * (vbq * rq - vbk * rk) * rk;
#pragma unroll
    for (int j = 0; j < 16; ++j) {
      wy[j] += cy * ksj[j]; wq[j] += cq * ksj[j]; wk[j] += ck * ksj[j]; wbr[j] += cb * ksj[j];
    }
  }
  __syncthreads();
  // batched LN + projection: wave w handles steps 4w..4w+3
  for (int k2 = 0; k2 < 4; ++k2) {
    const int sidx = w * 4 + k2;
    const float4 y4 = ((const float4*)ymat[sidx])[lane];
    const float s1 = wave_sum64(y4.x + y4.y + y4.z + y4.w);
    const float s2 = wave_sum64(y4.x * y4.x + y4.y * y4.y + y4.z * y4.z + y4.w * y4.w);
    float S[cNC];
#pragma unroll
    for (int c = 0; c < cNC; ++c) {
      const float4 g4 = ((const float4*)gwm[c])[lane];
      S[c] = wave_sum64(y4.x * g4.x + y4.y * g4.y + y4.z * g4.z + y4.w * g4.w);
    }
    if (lane == 0) {
      const float m = s1 * (1.f / 256.f);
      const float var = s2 * (1.f / 256.f) - m * m;
      const float rst = rsqrtf(var + LEPS);
#pragma unroll
      for (int c = 0; c < cNC; ++c) {
        outp[(size_t)(sidx * cB + b) * cNC + c] =
            outb[c] + rst * S[c] - rst * m * GBs[c] + GBs[5 + c];
      }
    }
  }
}

extern "C" void kernel_launch(void* const* d_in, const int* in_sizes, int n_in,
                              void* d_out, int out_size, void* d_ws, size_t ws_size,
                              hipStream_t stream) {
  const float* x     = (const float*)d_in[0];
  const int*   fb    = (const int*)d_in[1];
  const float* inW   = (const float*)d_in[2];
  const float* inb   = (const float*)d_in[3];
  const float* tkWy  = (const float*)d_in[4];
  const float* tkWq  = (const float*)d_in[5];
  const float* tkWk  = (const float*)d_in[6];
  const float* tkwb  = (const float*)d_in[7];
  const float* tklng = (const float*)d_in[8];
  const float* tklnb = (const float*)d_in[9];
  const float* tkmg  = (const float*)d_in[10];
  const float* tkmb  = (const float*)d_in[11];
  const float* tkmW1 = (const float*)d_in[12];
  const float* tkmb1 = (const float*)d_in[13];
  const float* tkmW2 = (const float*)d_in[14];
  const float* tkmb2 = (const float*)d_in[15];
  const float* chWy  = (const float*)d_in[16];
  const float* chWq  = (const float*)d_in[17];
  const float* chWk  = (const float*)d_in[18];
  const float* chwb  = (const float*)d_in[19];
  const float* chlng = (const float*)d_in[20];
  const float* chlnb = (const float*)d_in[21];
  const float* chmg  = (const float*)d_in[22];
  const float* chmb  = (const float*)d_in[23];
  const float* chmW1 = (const float*)d_in[24];
  const float* chmb1 = (const float*)d_in[25];
  const float* chmW2 = (const float*)d_in[26];
  const float* chmb2 = (const float*)d_in[27];
  const float* flng  = (const float*)d_in[28];
  const float* flnb  = (const float*)d_in[29];
  const float* oWy   = (const float*)d_in[30];
  const float* oWq   = (const float*)d_in[31];
  const float* oWk   = (const float*)d_in[32];
  const float* owb   = (const float*)d_in[33];
  const float* olng  = (const float*)d_in[34];
  const float* olnb  = (const float*)d_in[35];
  const float* outW  = (const float*)d_in[36];
  const float* outb  = (const float*)d_in[37];

  float* h    = (float*)d_ws;                               // (S,B,P,D) fp32 = 2 MB
  float* gbuf = h + (size_t)cS * cB * cP * cD;              // (S,B,D)
  float* outp = (float*)d_out;                              // (S,B,NC) fp32

  k_embed<<<dim3(cS * cB * cP), dim3(256), 0, stream>>>(x, fb, inW, inb, h);
  for (int i = 0; i < 2; ++i) {
    k_tok_srwm<<<dim3(128), dim3(256), 0, stream>>>(
        h, tkWy + i * 256, tkWq + i * 256, tkWk + i * 256, tkwb + i * 64,
        tklng + i * 16, tklnb + i * 16);
    k_tok_mixer<<<dim3(cS * cB), dim3(256), 0, stream>>>(
        h, tkmg + i * 256, tkmb + i * 256, tkmW1 + i * 1024, tkmb1 + i * 64,
        tkmW2 + i * 1024, tkmb2 + i * 16);
    k_ch_srwm_mix<<<dim3(cB * cP), dim3(256), 0, stream>>>(
        h, chWy + i * 4096, chWq + i * 4096, chWk + i * 4096, chwb + i * 1024,
        chlng + i * 256, chlnb + i * 256,
        chmg + i * 256, chmb + i * 256, chmW1 + i * 32768, chmb1 + i * 128,
        chmW2 + i * 32768, chmb2 + i * 256);
  }
  k_fln_mean<<<dim3(cS * cB), dim3(256), 0, stream>>>(h, flng, flnb, gbuf);
  k_out_srwm<<<dim3(cB), dim3(256), 0, stream>>>(
      gbuf, outp, oWy, oWq, oWk, owb, olng, olnb, outW, outb);
}